// Round 4
// baseline (2059.665 us; speedup 1.0000x reference)
//
#include <hip/hip_runtime.h>

#define F 64
#define TPB 256
#define BN_EPS 1e-5f

// ---- CSR build ----------------------------------------------------------

__global__ void k_hist(const int* __restrict__ dst, int* __restrict__ deg, int E) {
    int e = blockIdx.x * blockDim.x + threadIdx.x;
    if (e < E) atomicAdd(&deg[dst[e]], 1);
}

// single-block exclusive scan of deg[N] -> offs[N+1] (and cursor copy)
__global__ void k_scan(const int* __restrict__ deg, int* __restrict__ offs,
                       int* __restrict__ cursor, int N) {
    __shared__ int part[TPB];
    int t = threadIdx.x;
    int chunk = (N + TPB - 1) / TPB;
    int lo = t * chunk, hi = min(lo + chunk, N);
    int s = 0;
    for (int i = lo; i < hi; ++i) s += deg[i];
    part[t] = s;
    __syncthreads();
    for (int d = 1; d < TPB; d <<= 1) {
        int add = (t >= d) ? part[t - d] : 0;
        __syncthreads();
        part[t] += add;
        __syncthreads();
    }
    int run = part[t] - s;  // exclusive prefix
    for (int i = lo; i < hi; ++i) {
        offs[i] = run;
        cursor[i] = run;
        run += deg[i];
    }
    if (t == TPB - 1) offs[N] = run;
}

__global__ void k_fill(const int* __restrict__ src, const int* __restrict__ dst,
                       int* __restrict__ cursor, int* __restrict__ csr_src, int E) {
    int e = blockIdx.x * blockDim.x + threadIdx.x;
    if (e >= E) return;
    int pos = atomicAdd(&cursor[dst[e]], 1);
    csr_src[pos] = src[e];
}

// ---- layer kernels ------------------------------------------------------

// Yf = x @ W + bias (init for jumping-knowledge accumulator)
__global__ void k_accmm0(const float* __restrict__ A, const float* __restrict__ W,
                         const float* __restrict__ bias, float* __restrict__ Yf, int N) {
    __shared__ float Wl[F * F];
    int t = threadIdx.x;
    for (int i = t; i < F * F; i += TPB) Wl[i] = W[i];
    __syncthreads();
    int j = t & 63, r0 = t >> 6;
    int rowbase = blockIdx.x * 64;
    float bj = bias[j];
    for (int r = r0; r < 64; r += 4) {
        int row = rowbase + r;
        if (row >= N) break;
        const float* a = A + (size_t)row * F;
        float acc = bj;
#pragma unroll
        for (int f = 0; f < F; ++f) acc += a[f] * Wl[f * F + j];
        Yf[(size_t)row * F + j] = acc;
    }
}

// Fused: CSR gather-aggregate (h + sum of neighbors) -> @W1 + b1 -> Y, BN stats
// block = 256 threads = 4 waves; wave handles 16 nodes; W column j in registers.
__global__ void k_layerA(const float* __restrict__ h, const int* __restrict__ offs,
                         const int* __restrict__ csr_src,
                         const float* __restrict__ W, const float* __restrict__ bias,
                         float* __restrict__ Y, float* __restrict__ stats, int N) {
    __shared__ float rowbuf[4 * F];
    __shared__ float red[TPB];
    int t = threadIdx.x;
    int j = t & 63, w = t >> 6;
    float wcol[F];
#pragma unroll
    for (int f = 0; f < F; ++f) wcol[f] = W[f * F + j];
    float bj = bias[j];
    float s1 = 0.f, s2 = 0.f;
    int nodebase = blockIdx.x * 64 + w * 16;
    for (int r = 0; r < 16; ++r) {
        int node = nodebase + r;
        if (node >= N) break;
        float agg = h[(size_t)node * F + j];            // GIN self term (eps=0)
        int start = offs[node], end = offs[node + 1];
        for (int base = start; base < end; base += 64) {
            int cnt = end - base; if (cnt > 64) cnt = 64;
            int idx = (j < cnt) ? csr_src[base + j] : 0;
#pragma unroll 4
            for (int k = 0; k < cnt; ++k) {
                int s = __shfl(idx, k, 64);
                agg += h[(size_t)s * F + j];
            }
        }
        // row -> LDS (wave-private region; DS ops in-order within a wave)
        rowbuf[w * F + j] = agg;
        float acc = bj;
#pragma unroll
        for (int f = 0; f < F; ++f) acc += rowbuf[w * F + f] * wcol[f];
        Y[(size_t)node * F + j] = acc;
        s1 += acc;
        s2 += acc * acc;
    }
    red[t] = s1; __syncthreads();
    if (w == 0) atomicAdd(&stats[j], red[j] + red[64 + j] + red[128 + j] + red[192 + j]);
    __syncthreads();
    red[t] = s2; __syncthreads();
    if (w == 0) atomicAdd(&stats[64 + j], red[j] + red[64 + j] + red[128 + j] + red[192 + j]);
}

// Fused: BN(Y)+ReLU -> @W2+b2 -> ReLU -> Hout; Yf += Hout @ Wj (JK chunk);
// optionally accumulate head BN stats of final Yf.
__global__ void k_layerB(const float* __restrict__ Y, const float* __restrict__ stats,
                         const float* __restrict__ g, const float* __restrict__ bt,
                         const float* __restrict__ W2, const float* __restrict__ b2v,
                         const float* __restrict__ Wj,
                         float* __restrict__ Hout, float* __restrict__ Yf,
                         float* __restrict__ stats5, int N, int doHead) {
    __shared__ float W2l[F * F];
    __shared__ float Wjl[F * F];
    __shared__ float Al[F * F];
    __shared__ float Bl[F * F];
    __shared__ float scale[F], shift[F];
    __shared__ float red[TPB];
    int t = threadIdx.x;
    for (int i = t; i < F * F; i += TPB) { W2l[i] = W2[i]; Wjl[i] = Wj[i]; }
    if (t < F) {
        float mu = stats[t] / (float)N;
        float var = stats[64 + t] / (float)N - mu * mu;
        float rs = rsqrtf(var + BN_EPS);
        float sc = rs * g[t];
        scale[t] = sc;
        shift[t] = bt[t] - mu * sc;
    }
    __syncthreads();
    int j = t & 63, r0 = t >> 6;
    int rowbase = blockIdx.x * 64;
    for (int r = r0; r < 64; r += 4) {
        int row = rowbase + r;
        float v = 0.f;
        if (row < N) v = fmaxf(Y[(size_t)row * F + j] * scale[j] + shift[j], 0.f);
        Al[r * F + j] = v;
    }
    __syncthreads();
    float bj = b2v[j];
    for (int r = r0; r < 64; r += 4) {
        int row = rowbase + r;
        float acc = bj;
#pragma unroll
        for (int f = 0; f < F; ++f) acc += Al[r * F + f] * W2l[f * F + j];
        float v = fmaxf(acc, 0.f);
        Bl[r * F + j] = v;
        if (row < N) Hout[(size_t)row * F + j] = v;
    }
    __syncthreads();
    float s1 = 0.f, s2 = 0.f;
    for (int r = r0; r < 64; r += 4) {
        int row = rowbase + r;
        if (row >= N) break;
        float acc = Yf[(size_t)row * F + j];
#pragma unroll
        for (int f = 0; f < F; ++f) acc += Bl[r * F + f] * Wjl[f * F + j];
        Yf[(size_t)row * F + j] = acc;
        s1 += acc;
        s2 += acc * acc;
    }
    if (doHead) {
        red[t] = s1; __syncthreads();
        if (r0 == 0) atomicAdd(&stats5[j], red[j] + red[64 + j] + red[128 + j] + red[192 + j]);
        __syncthreads();
        red[t] = s2; __syncthreads();
        if (r0 == 0) atomicAdd(&stats5[64 + j], red[j] + red[64 + j] + red[128 + j] + red[192 + j]);
    }
}

// BN(Yf)+ReLU -> @mlpW2+b2 -> pooled atomicAdd into out[graph] (run-length flush)
__global__ void k_final(const float* __restrict__ Yf, const float* __restrict__ stats,
                        const float* __restrict__ g, const float* __restrict__ bt,
                        const float* __restrict__ W2, const float* __restrict__ b2v,
                        const int* __restrict__ batch, float* __restrict__ out, int N) {
    __shared__ float Wl[F * F];
    __shared__ float Al[F * F];
    __shared__ float scale[F], shift[F];
    int t = threadIdx.x;
    for (int i = t; i < F * F; i += TPB) Wl[i] = W2[i];
    if (t < F) {
        float mu = stats[t] / (float)N;
        float var = stats[64 + t] / (float)N - mu * mu;
        float rs = rsqrtf(var + BN_EPS);
        float sc = rs * g[t];
        scale[t] = sc;
        shift[t] = bt[t] - mu * sc;
    }
    __syncthreads();
    int j = t & 63, r0 = t >> 6;
    int rowbase = blockIdx.x * 64;
    for (int r = r0; r < 64; r += 4) {
        int row = rowbase + r;
        float v = 0.f;
        if (row < N) v = fmaxf(Yf[(size_t)row * F + j] * scale[j] + shift[j], 0.f);
        Al[r * F + j] = v;
    }
    __syncthreads();
    float bj = b2v[j];
    int curg = -1;
    float accg = 0.f;
    for (int r = r0; r < 64; r += 4) {
        int row = rowbase + r;
        if (row >= N) break;
        float acc = bj;
#pragma unroll
        for (int f = 0; f < F; ++f) acc += Al[r * F + f] * Wl[f * F + j];
        int gid = batch[row];
        if (gid != curg) {
            if (curg >= 0) atomicAdd(&out[(size_t)curg * F + j], accg);
            curg = gid;
            accg = 0.f;
        }
        accg += acc;
    }
    if (curg >= 0) atomicAdd(&out[(size_t)curg * F + j], accg);
}

// ---- launcher -----------------------------------------------------------

extern "C" void kernel_launch(void* const* d_in, const int* in_sizes, int n_in,
                              void* d_out, int out_size, void* d_ws, size_t ws_size,
                              hipStream_t stream) {
    const float* x      = (const float*)d_in[0];
    const int*   ei     = (const int*)d_in[1];
    const int*   batch  = (const int*)d_in[2];
    const float* convW1 = (const float*)d_in[3];
    const float* convb1 = (const float*)d_in[4];
    const float* convg  = (const float*)d_in[5];
    const float* convbt = (const float*)d_in[6];
    const float* convW2 = (const float*)d_in[7];
    const float* convb2 = (const float*)d_in[8];
    const float* mlpW1  = (const float*)d_in[9];
    const float* mlpb1  = (const float*)d_in[10];
    const float* mlpg   = (const float*)d_in[11];
    const float* mlpbt  = (const float*)d_in[12];
    const float* mlpW2  = (const float*)d_in[13];
    const float* mlpb2  = (const float*)d_in[14];

    const int N = in_sizes[0] / F;             // 50000
    const int E = in_sizes[1] / 2;             // 800000
    const int L = in_sizes[3] / (F * F);       // 5

    const int* src = ei;
    const int* dst = ei + E;

    char* w = (char*)d_ws;
    size_t off = 0;
    auto alloc = [&](size_t bytes) {
        void* p = w + off;
        off = (off + bytes + 255) & ~(size_t)255;
        return p;
    };
    float* hA      = (float*)alloc((size_t)N * F * 4);
    float* hB      = (float*)alloc((size_t)N * F * 4);
    float* Ytmp    = (float*)alloc((size_t)N * F * 4);
    float* Yf      = (float*)alloc((size_t)N * F * 4);
    int*   deg     = (int*)alloc((size_t)N * 4);
    int*   offs    = (int*)alloc((size_t)(N + 1) * 4);
    int*   cursor  = (int*)alloc((size_t)N * 4);
    int*   csr_src = (int*)alloc((size_t)E * 4);
    float* stats   = (float*)alloc((size_t)(L + 1) * 128 * 4);

    hipMemsetAsync(deg, 0, (size_t)N * 4, stream);
    hipMemsetAsync(stats, 0, (size_t)(L + 1) * 128 * 4, stream);
    hipMemsetAsync(d_out, 0, (size_t)out_size * 4, stream);

    const int edgeBlocks = (E + TPB - 1) / TPB;
    const int rowBlocks  = (N + 63) / 64;

    // CSR build (once per call; reused by all 5 layers)
    k_hist<<<edgeBlocks, TPB, 0, stream>>>(dst, deg, E);
    k_scan<<<1, TPB, 0, stream>>>(deg, offs, cursor, N);
    k_fill<<<edgeBlocks, TPB, 0, stream>>>(src, dst, cursor, csr_src, E);

    // JK init: Yf = x @ mlpW1[chunk 0] + mlpb1
    k_accmm0<<<rowBlocks, TPB, 0, stream>>>(x, mlpW1, mlpb1, Yf, N);

    const float* h_cur = x;
    for (int l = 0; l < L; ++l) {
        float* h_next = (l & 1) ? hB : hA;
        k_layerA<<<rowBlocks, TPB, 0, stream>>>(h_cur, offs, csr_src,
                                                convW1 + l * F * F, convb1 + l * F,
                                                Ytmp, stats + l * 128, N);
        k_layerB<<<rowBlocks, TPB, 0, stream>>>(Ytmp, stats + l * 128,
                                                convg + l * F, convbt + l * F,
                                                convW2 + l * F * F, convb2 + l * F,
                                                mlpW1 + (l + 1) * F * F,
                                                h_next, Yf, stats + L * 128, N,
                                                l == L - 1);
        h_cur = h_next;
    }

    k_final<<<rowBlocks, TPB, 0, stream>>>(Yf, stats + L * 128, mlpg, mlpbt,
                                           mlpW2, mlpb2, batch, (float*)d_out, N);
}

// Round 5
// 950.156 us; speedup vs baseline: 2.1677x; 2.1677x over previous
//
#include <hip/hip_runtime.h>

#define F 64
#define TPB 256
#define BN_EPS 1e-5f

__device__ __forceinline__ float lane_bcast(float v, int l) {
    return __int_as_float(__builtin_amdgcn_readlane(__float_as_int(v), l));
}
__device__ __forceinline__ int lane_bcast_i(int v, int l) {
    return __builtin_amdgcn_readlane(v, l);
}

// ---- CSR build ----------------------------------------------------------

__global__ void k_hist(const int* __restrict__ dst, int* __restrict__ deg, int E) {
    int e = blockIdx.x * blockDim.x + threadIdx.x;
    if (e < E) atomicAdd(&deg[dst[e]], 1);
}

__global__ void k_scan(const int* __restrict__ deg, int* __restrict__ offs,
                       int* __restrict__ cursor, int N) {
    __shared__ int part[TPB];
    int t = threadIdx.x;
    int chunk = (N + TPB - 1) / TPB;
    int lo = t * chunk, hi = min(lo + chunk, N);
    int s = 0;
    for (int i = lo; i < hi; ++i) s += deg[i];
    part[t] = s;
    __syncthreads();
    for (int d = 1; d < TPB; d <<= 1) {
        int add = (t >= d) ? part[t - d] : 0;
        __syncthreads();
        part[t] += add;
        __syncthreads();
    }
    int run = part[t] - s;
    for (int i = lo; i < hi; ++i) {
        offs[i] = run;
        cursor[i] = run;
        run += deg[i];
    }
    if (t == TPB - 1) offs[N] = run;
}

__global__ void k_fill(const int* __restrict__ src, const int* __restrict__ dst,
                       int* __restrict__ cursor, int* __restrict__ csr_src, int E) {
    int e = blockIdx.x * blockDim.x + threadIdx.x;
    if (e >= E) return;
    int pos = atomicAdd(&cursor[dst[e]], 1);
    csr_src[pos] = src[e];
}

// ---- fused gather + GEMM1 + BN stats ------------------------------------
// wave = 64 lanes; lane j owns output col j (W1 col j in 64 VGPRs).
// Per node: coalesced row loads (self + neighbors via readlane-uniform base),
// then GEMM via readlane broadcast (VALU only, no LDS).
__global__ void k_gather_gemm(const float* __restrict__ h, const int* __restrict__ offs,
                              const int* __restrict__ csr,
                              const float* __restrict__ W, const float* __restrict__ bias,
                              float* __restrict__ Y, float* __restrict__ stats,
                              int N, int nodesPerWave) {
    int t = threadIdx.x;
    int lane = t & 63, w = t >> 6;
    float wcol[F];
#pragma unroll
    for (int f = 0; f < F; ++f) wcol[f] = W[f * F + lane];
    float bj = bias[lane];
    int node0 = (blockIdx.x * 4 + w) * nodesPerWave;
    float s1 = 0.f, s2 = 0.f;
    for (int r = 0; r < nodesPerWave; ++r) {
        int node = node0 + r;
        if (node >= N) break;
        float agg = h[(size_t)node * F + lane];          // GIN self term (eps=0)
        int start = offs[node], end = offs[node + 1];
        for (int base = start; base < end; base += 64) {
            int cnt = end - base; if (cnt > 64) cnt = 64;
            int idx = (lane < cnt) ? csr[base + lane] : 0;
            int k = 0;
            for (; k + 4 <= cnt; k += 4) {
                int n0 = lane_bcast_i(idx, k), n1 = lane_bcast_i(idx, k + 1);
                int n2 = lane_bcast_i(idx, k + 2), n3 = lane_bcast_i(idx, k + 3);
                float v0 = h[(size_t)n0 * F + lane];
                float v1 = h[(size_t)n1 * F + lane];
                float v2 = h[(size_t)n2 * F + lane];
                float v3 = h[(size_t)n3 * F + lane];
                agg += (v0 + v1) + (v2 + v3);
            }
            for (; k < cnt; ++k)
                agg += h[(size_t)lane_bcast_i(idx, k) * F + lane];
        }
        float acc = bj;
#pragma unroll
        for (int f = 0; f < F; ++f) acc += lane_bcast(agg, f) * wcol[f];
        Y[(size_t)node * F + lane] = acc;
        s1 += acc;
        s2 += acc * acc;
    }
    __shared__ float red[TPB];
    red[t] = s1; __syncthreads();
    if (w == 0) atomicAdd(&stats[lane], red[lane] + red[64 + lane] + red[128 + lane] + red[192 + lane]);
    __syncthreads();
    red[t] = s2; __syncthreads();
    if (w == 0) atomicAdd(&stats[64 + lane], red[lane] + red[64 + lane] + red[128 + lane] + red[192 + lane]);
}

// ---- BN-apply + ReLU -> GEMM2 -> ReLU -> Hout ---------------------------
__global__ void k_bn_gemm(const float* __restrict__ Y, const float* __restrict__ stats,
                          const float* __restrict__ g, const float* __restrict__ bt,
                          const float* __restrict__ W2, const float* __restrict__ b2,
                          float* __restrict__ Hout, int N, int rowsPerWave) {
    int t = threadIdx.x;
    int lane = t & 63, w = t >> 6;
    float wcol[F];
#pragma unroll
    for (int f = 0; f < F; ++f) wcol[f] = W2[f * F + lane];
    float mu = stats[lane] / (float)N;
    float var = stats[64 + lane] / (float)N - mu * mu;
    float rs = rsqrtf(var + BN_EPS);
    float sc = rs * g[lane];
    float sh = bt[lane] - mu * sc;
    float bj = b2[lane];
    int row0 = (blockIdx.x * 4 + w) * rowsPerWave;
    for (int r = 0; r < rowsPerWave; ++r) {
        int row = row0 + r;
        if (row >= N) break;
        float v = fmaxf(Y[(size_t)row * F + lane] * sc + sh, 0.f);
        float acc = bj;
#pragma unroll
        for (int f = 0; f < F; ++f) acc += lane_bcast(v, f) * wcol[f];
        Hout[(size_t)row * F + lane] = fmaxf(acc, 0.f);
    }
}

// ---- jumping-knowledge accumulate: Yf (+)= Hin @ Wj [+ bias]; opt head stats
__global__ void k_jk(const float* __restrict__ Hin, const float* __restrict__ Wj,
                     const float* __restrict__ bias, float* __restrict__ Yf,
                     float* __restrict__ stats5, int N, int rowsPerWave,
                     int initFlag, int doHead) {
    int t = threadIdx.x;
    int lane = t & 63, w = t >> 6;
    float wcol[F];
#pragma unroll
    for (int f = 0; f < F; ++f) wcol[f] = Wj[f * F + lane];
    float bj = bias[lane];
    int row0 = (blockIdx.x * 4 + w) * rowsPerWave;
    float s1 = 0.f, s2 = 0.f;
    for (int r = 0; r < rowsPerWave; ++r) {
        int row = row0 + r;
        if (row >= N) break;
        float v = Hin[(size_t)row * F + lane];
        float acc = initFlag ? bj : Yf[(size_t)row * F + lane];
#pragma unroll
        for (int f = 0; f < F; ++f) acc += lane_bcast(v, f) * wcol[f];
        Yf[(size_t)row * F + lane] = acc;
        if (doHead) { s1 += acc; s2 += acc * acc; }
    }
    if (doHead) {
        __shared__ float red[TPB];
        red[t] = s1; __syncthreads();
        if (w == 0) atomicAdd(&stats5[lane], red[lane] + red[64 + lane] + red[128 + lane] + red[192 + lane]);
        __syncthreads();
        red[t] = s2; __syncthreads();
        if (w == 0) atomicAdd(&stats5[64 + lane], red[lane] + red[64 + lane] + red[128 + lane] + red[192 + lane]);
    }
}

// ---- head: BN(Yf)+ReLU -> @mlpW2+b2 -> pooled add into out[graph] -------
__global__ void k_final(const float* __restrict__ Yf, const float* __restrict__ stats,
                        const float* __restrict__ g, const float* __restrict__ bt,
                        const float* __restrict__ W2, const float* __restrict__ b2,
                        const int* __restrict__ batch, float* __restrict__ out,
                        int N, int rowsPerWave) {
    int t = threadIdx.x;
    int lane = t & 63, w = t >> 6;
    float wcol[F];
#pragma unroll
    for (int f = 0; f < F; ++f) wcol[f] = W2[f * F + lane];
    float mu = stats[lane] / (float)N;
    float var = stats[64 + lane] / (float)N - mu * mu;
    float rs = rsqrtf(var + BN_EPS);
    float sc = rs * g[lane];
    float sh = bt[lane] - mu * sc;
    float bj = b2[lane];
    int row0 = (blockIdx.x * 4 + w) * rowsPerWave;
    int curg = -1;
    float accg = 0.f;
    for (int r = 0; r < rowsPerWave; ++r) {
        int row = row0 + r;
        if (row >= N) break;
        float v = fmaxf(Yf[(size_t)row * F + lane] * sc + sh, 0.f);
        float acc = bj;
#pragma unroll
        for (int f = 0; f < F; ++f) acc += lane_bcast(v, f) * wcol[f];
        int gid = batch[row];                      // wave-uniform (rows sorted)
        if (gid != curg) {
            if (curg >= 0) atomicAdd(&out[(size_t)curg * F + lane], accg);
            curg = gid;
            accg = 0.f;
        }
        accg += acc;
    }
    if (curg >= 0) atomicAdd(&out[(size_t)curg * F + lane], accg);
}

// ---- launcher -----------------------------------------------------------

extern "C" void kernel_launch(void* const* d_in, const int* in_sizes, int n_in,
                              void* d_out, int out_size, void* d_ws, size_t ws_size,
                              hipStream_t stream) {
    const float* x      = (const float*)d_in[0];
    const int*   ei     = (const int*)d_in[1];
    const int*   batch  = (const int*)d_in[2];
    const float* convW1 = (const float*)d_in[3];
    const float* convb1 = (const float*)d_in[4];
    const float* convg  = (const float*)d_in[5];
    const float* convbt = (const float*)d_in[6];
    const float* convW2 = (const float*)d_in[7];
    const float* convb2 = (const float*)d_in[8];
    const float* mlpW1  = (const float*)d_in[9];
    const float* mlpb1  = (const float*)d_in[10];
    const float* mlpg   = (const float*)d_in[11];
    const float* mlpbt  = (const float*)d_in[12];
    const float* mlpW2  = (const float*)d_in[13];
    const float* mlpb2  = (const float*)d_in[14];

    const int N = in_sizes[0] / F;             // 50000
    const int E = in_sizes[1] / 2;             // 800000
    const int L = in_sizes[3] / (F * F);       // 5

    const int* src = ei;
    const int* dst = ei + E;

    char* w = (char*)d_ws;
    size_t off = 0;
    auto alloc = [&](size_t bytes) {
        void* p = w + off;
        off = (off + bytes + 255) & ~(size_t)255;
        return p;
    };
    float* hA      = (float*)alloc((size_t)N * F * 4);
    float* hB      = (float*)alloc((size_t)N * F * 4);
    float* Ytmp    = (float*)alloc((size_t)N * F * 4);
    float* Yf      = (float*)alloc((size_t)N * F * 4);
    int*   deg     = (int*)alloc((size_t)N * 4);
    int*   offs    = (int*)alloc((size_t)(N + 1) * 4);
    int*   cursor  = (int*)alloc((size_t)N * 4);
    int*   csr_src = (int*)alloc((size_t)E * 4);
    float* stats   = (float*)alloc((size_t)(L + 1) * 128 * 4);

    hipMemsetAsync(deg, 0, (size_t)N * 4, stream);
    hipMemsetAsync(stats, 0, (size_t)(L + 1) * 128 * 4, stream);
    hipMemsetAsync(d_out, 0, (size_t)out_size * 4, stream);

    const int edgeBlocks = (E + TPB - 1) / TPB;

    // CSR build (reused by all layers)
    k_hist<<<edgeBlocks, TPB, 0, stream>>>(dst, deg, E);
    k_scan<<<1, TPB, 0, stream>>>(deg, offs, cursor, N);
    k_fill<<<edgeBlocks, TPB, 0, stream>>>(src, dst, cursor, csr_src, E);

    const int NPW_A = 8;    // nodes per wave, gather kernel
    const int RPW   = 8;    // rows per wave, dense kernels
    const int RPW_F = 16;   // rows per wave, final (fewer pool atomics)
    const int blocksA = (N + 4 * NPW_A - 1) / (4 * NPW_A);
    const int blocksD = (N + 4 * RPW - 1) / (4 * RPW);
    const int blocksF = (N + 4 * RPW_F - 1) / (4 * RPW_F);

    // JK init: Yf = x @ mlpW1[chunk 0] + mlpb1
    k_jk<<<blocksD, TPB, 0, stream>>>(x, mlpW1, mlpb1, Yf, stats + L * 128, N, RPW, 1, 0);

    const float* h_cur = x;
    for (int l = 0; l < L; ++l) {
        float* h_next = (l & 1) ? hB : hA;
        k_gather_gemm<<<blocksA, TPB, 0, stream>>>(h_cur, offs, csr_src,
                                                   convW1 + l * F * F, convb1 + l * F,
                                                   Ytmp, stats + l * 128, N, NPW_A);
        k_bn_gemm<<<blocksD, TPB, 0, stream>>>(Ytmp, stats + l * 128,
                                               convg + l * F, convbt + l * F,
                                               convW2 + l * F * F, convb2 + l * F,
                                               h_next, N, RPW);
        k_jk<<<blocksD, TPB, 0, stream>>>(h_next, mlpW1 + (l + 1) * F * F, mlpb1,
                                          Yf, stats + L * 128, N, RPW, 0, l == L - 1);
        h_cur = h_next;
    }

    k_final<<<blocksF, TPB, 0, stream>>>(Yf, stats + L * 128, mlpg, mlpbt,
                                         mlpW2, mlpb2, batch, (float*)d_out, N, RPW_F);
}